// Round 12
// baseline (248.884 us; speedup 1.0000x reference)
//
#include <hip/hip_runtime.h>
#include <hip/hip_bf16.h>
#include <math.h>

typedef __attribute__((ext_vector_type(8))) short short8;
typedef __attribute__((ext_vector_type(4))) float f32x4;

// 8-way bucketed CSR, entries ushort (dst < 65536; N=50000).
// bucket = blockIdx&7 (~XCD under round-robin). Layout [8][N][CAP8]: every CSR line
// is written by exactly one XCD. Per (v,b) count ~Poisson(2), P(>16)~2e-9.
#define CAP8 16
#define EPT  4   // edges per fill thread (r9's measured-best fill: EPT=4, 1:1 interleave)

__device__ __forceinline__ float bf2f(unsigned short u) {
    union { unsigned int i; float f; } c; c.i = ((unsigned int)u) << 16; return c.f;
}
__device__ __forceinline__ unsigned short f2bf(float f) {
    __hip_bfloat16 h = __float2bfloat16(f);   // RNE
    union { __hip_bfloat16 h; unsigned short u; } c; c.h = h; return c.u;
}
__device__ __forceinline__ float gelu_exact(float x) {
    return 0.5f * x * (1.0f + erff(x * 0.7071067811865475f));
}
__device__ __forceinline__ short8 ldcvt8(const float* p) {
    float4 f0 = *(const float4*)p;
    float4 f1 = *(const float4*)(p + 4);
    short8 a;
    a[0] = (short)f2bf(f0.x); a[1] = (short)f2bf(f0.y);
    a[2] = (short)f2bf(f0.z); a[3] = (short)f2bf(f0.w);
    a[4] = (short)f2bf(f1.x); a[5] = (short)f2bf(f1.y);
    a[6] = (short)f2bf(f1.z); a[7] = (short)f2bf(f1.w);
    return a;
}
// XOR swizzle for [rows][128] bf16 LDS tile (row stride 256B): 16B-granular, bijective per 8-row stripe.
__device__ __forceinline__ int swz(int row, int colbyte) {
    return row * 256 + (colbyte ^ ((row & 7) << 4));
}

// volatile asm 16B global load: cannot be sunk/reordered by the compiler (the r5 failure mode).
__device__ __forceinline__ short8 ga16(const unsigned short* p) {
    short8 r;
    asm volatile("global_load_dwordx4 %0, %1, off" : "=v"(r) : "v"(p));
    return r;
}
#define GWAIT(NVM) { \
    asm volatile("s_waitcnt vmcnt(" #NVM ")" ::: "memory"); \
    __builtin_amdgcn_sched_barrier(0); }

__device__ __forceinline__ int detect_flag(const int* ei, int E) {
    int orv = 0;
    int lim = (E < 64) ? E : 64;
    for (int i = 0; i < lim; i++) orv |= ei[2 * i + 1];
    return (orv == 0) ? 1 : 0;
}
__device__ __forceinline__ int ld_src(const int* ei, int flag, int E, int e) {
    if (flag) { int2 p = *(const int2*)(ei + 2 * (size_t)e); return p.x; }
    return ei[e];
}
__device__ __forceinline__ int ld_dst(const int* ei, int flag, int E, int e) {
    if (flag) { int2 p = *(const int2*)(ei + 2 * (size_t)(E + e)); return p.x; }
    return ei[E + e];
}

// ---------------- init: zero cursors + convert weights to bf16 ----------------
__launch_bounds__(256)
__global__ void init_kernel(const float* __restrict__ Wn, const float* __restrict__ We,
                            const float* __restrict__ Wu,
                            unsigned short* __restrict__ Wnb, unsigned short* __restrict__ Web,
                            unsigned short* __restrict__ Wub,
                            int* __restrict__ cursor8, int N) {
    const int stride = gridDim.x * 256;
    const int t = blockIdx.x * 256 + threadIdx.x;
    for (int i = t; i < 8 * N; i += stride) cursor8[i] = 0;
    for (int i = t; i < 128 * 128; i += stride) Wnb[i] = f2bf(Wn[i]);
    for (int i = t; i < 128 * 256; i += stride) Web[i] = f2bf(We[i]);
    for (int i = t; i < 128 * 384; i += stride) Wub[i] = f2bf(Wu[i]);
}

// ---------------- GEMM1 body: node = x@Wn^T + bn (bf16); Apre0 = gelu(node) ----------------
__device__ __forceinline__ void gemm1_body(int bid,
                                           const float* __restrict__ x,
                                           const unsigned short* __restrict__ Wnb,  // [128][128] bf16
                                           const float* __restrict__ bias,
                                           unsigned short* __restrict__ node,
                                           unsigned short* __restrict__ Apre0,
                                           int N) {
    const int v0 = bid * 64;
    const int wave = threadIdx.x >> 6;
    const int lane = threadIdx.x & 63;
    const int m    = lane & 15;
    const int kq   = lane >> 4;

    short8 B[2][4];
#pragma unroll
    for (int ntl = 0; ntl < 2; ntl++) {
        const int j = (wave * 2 + ntl) * 16 + m;
#pragma unroll
        for (int kb = 0; kb < 4; kb++)
            B[ntl][kb] = *(const short8*)(Wnb + (size_t)j * 128 + kb * 32 + kq * 8);
    }

    f32x4 acc[4][2];
#pragma unroll
    for (int mt = 0; mt < 4; mt++)
#pragma unroll
        for (int ntl = 0; ntl < 2; ntl++) acc[mt][ntl] = (f32x4){0.f,0.f,0.f,0.f};

#pragma unroll
    for (int kb = 0; kb < 4; kb++) {
#pragma unroll
        for (int mt = 0; mt < 4; mt++) {
            const int row = v0 + mt * 16 + m;
            short8 a = (short8){0,0,0,0,0,0,0,0};
            if (row < N) a = ldcvt8(x + (size_t)row * 128 + kb * 32 + kq * 8);
#pragma unroll
            for (int ntl = 0; ntl < 2; ntl++)
                acc[mt][ntl] = __builtin_amdgcn_mfma_f32_16x16x32_bf16(a, B[ntl][kb], acc[mt][ntl], 0, 0, 0);
        }
    }

    const int ocol = lane & 15;
#pragma unroll
    for (int mt = 0; mt < 4; mt++) {
#pragma unroll
        for (int ntl = 0; ntl < 2; ntl++) {
            const int col = (wave * 2 + ntl) * 16 + ocol;
            const float bval = bias[col];
#pragma unroll
            for (int r = 0; r < 4; r++) {
                const int row = v0 + mt * 16 + (lane >> 4) * 4 + r;
                if (row < N) {
                    const float v = acc[mt][ntl][r] + bval;
                    node[(size_t)row * 128 + col]  = f2bf(v);
                    Apre0[(size_t)row * 128 + col] = f2bf(gelu_exact(v));
                }
            }
        }
    }
}

// ---------------- Kernel A: fill (EPT=4 edges/thread) interleaved 1:1 with GEMM1 (r9 config) ----
// Groups of 8 blocks keep bucket = blockIdx&7 uniform per XCD for both block types.
__launch_bounds__(256)
__global__ void fused_a(const float* __restrict__ x,
                        const unsigned short* __restrict__ Wnb,
                        const float* __restrict__ bn,
                        unsigned short* __restrict__ node,
                        unsigned short* __restrict__ Apre0,
                        const int* __restrict__ ei,
                        int* __restrict__ cursor8,          // [8][N]
                        unsigned short* __restrict__ csr8,  // [8][N][CAP8] ushort
                        int E, int N, int mblocks) {
    const int grp = blockIdx.x >> 3;
    if (grp & 1) {                                        // odd groups: gemm1
        const int mid = (grp >> 1) * 8 + (int)(blockIdx.x & 7);
        if (mid < mblocks) gemm1_body(mid, x, Wnb, bn, node, Apre0, N);
        return;
    }
    __shared__ int sflag;
    if (threadIdx.x == 0) sflag = detect_flag(ei, E);
    __syncthreads();
    const int fgrp = grp >> 1;
    const int b = (int)(blockIdx.x & 7);                  // ~XCD id under round-robin dispatch
    const int e0 = (fgrp * 8 + b) * (256 * EPT) + (int)threadIdx.x;

    int sv[EPT], dv[EPT], p[EPT];
    bool ok[EPT];
#pragma unroll
    for (int k = 0; k < EPT; k++) {
        const int e = e0 + k * 256;
        ok[k] = (e < E);
        sv[k] = 0; dv[k] = 0; p[k] = CAP8;
        if (ok[k]) { sv[k] = ld_src(ei, sflag, E, e); dv[k] = ld_dst(ei, sflag, E, e); }
    }
#pragma unroll
    for (int k = 0; k < EPT; k++) {
        ok[k] = ok[k] && (unsigned)sv[k] < (unsigned)N && (unsigned)dv[k] < (unsigned)N;
        if (ok[k]) p[k] = atomicAdd(&cursor8[(size_t)b * N + sv[k]], 1);
    }
#pragma unroll
    for (int k = 0; k < EPT; k++) {
        if (ok[k] && p[k] < CAP8)
            csr8[((size_t)b * N + sv[k]) * CAP8 + p[k]] = (unsigned short)dv[k];
    }
}

// ---- asm-pipelined gather (fused, M=16): wave owns 4 vertices; 8 volatile-asm loads/vertex
// (rows way+4u, u<8 covers deg<=32, sentinel row 0 beyond); depth-2 pipeline -> 16 in flight.
#define GISS(I, BUF) { \
    const int vl_ = wvb + (I); \
    const int dg_ = degI[vl_]; \
    _Pragma("unroll") \
    for (int u = 0; u < 8; u++) { \
        const int r_  = way + 4 * u; \
        const int id_ = (r_ < dg_) ? (int)listT[vl_ * 128 + r_] : 0; \
        BUF[u] = ga16(node + (size_t)id_ * 128 + sl * 8); \
    } }

#define GCONS(I, BUF) { \
    const int vl_ = wvb + (I); \
    const int v_  = v0 + vl_; \
    const int dg_ = degI[vl_]; \
    float acc_[8] = {0.f,0.f,0.f,0.f,0.f,0.f,0.f,0.f}; \
    _Pragma("unroll") \
    for (int u = 0; u < 8; u++) { \
        if (way + 4 * u < dg_) { \
            _Pragma("unroll") \
            for (int e = 0; e < 8; e++) acc_[e] += bf2f((unsigned short)BUF[u][e]); \
        } } \
    if (__builtin_expect(dg_ > 32, 0)) {   /* P~1e-4; compiler's own waits cover these loads */ \
        for (int n_ = 32 + way; n_ < dg_; n_ += 4) { \
            const int id_ = (int)listT[vl_ * 128 + n_]; \
            short8 t_ = *(const short8*)(node + (size_t)id_ * 128 + sl * 8); \
            _Pragma("unroll") \
            for (int e = 0; e < 8; e++) acc_[e] += bf2f((unsigned short)t_[e]); \
        } } \
    _Pragma("unroll") \
    for (int e = 0; e < 8; e++) { \
        acc_[e] += __shfl_xor(acc_[e], 16); \
        acc_[e] += __shfl_xor(acc_[e], 32); \
    } \
    if (v_ < N) { \
        if (way == 0) { \
            short8 o_; \
            _Pragma("unroll") \
            for (int e = 0; e < 8; e++) o_[e] = (short)f2bf(acc_[e]); \
            *(short8*)((char*)nbrT + swz(vl_, sl * 16)) = o_; \
        } else if (way == 1) { \
            short8 o_; \
            _Pragma("unroll") \
            for (int e = 0; e < 8; e++) o_[e] = (short)f2bf(gelu_exact(acc_[e])); \
            *(short8*)((char*)gnbrT + swz(vl_, sl * 16)) = o_; \
        } } }

// ---------------- Kernel B: asm gather -> GEMM2 -> GEMM3 per 16-row tile ----------------
// M=16: 3125 blocks (12.2/CU), ~13KB LDS -> 8 blocks/CU (32 waves) vs M=32's 6 -> more
// resident gather waves (the measured BW~occupancy lever from r8 vs r9).
__launch_bounds__(256)
__global__ void fused_b(const int* __restrict__ cursor8,
                        const unsigned short* __restrict__ csr8,
                        const unsigned short* __restrict__ node,
                        const unsigned short* __restrict__ Apre0,
                        const unsigned short* __restrict__ Web,  // [128][256] bf16
                        const float* __restrict__ be,
                        const unsigned short* __restrict__ Wub,  // [128][384] bf16
                        const float* __restrict__ bu,
                        float* __restrict__ out, int N) {
    __shared__ unsigned short nbrT [16 * 128];   // raw nbr sum bf16, swizzled
    __shared__ unsigned short gnbrT[16 * 128];   // gelu(nbr sum) bf16, swizzled
    __shared__ unsigned short scratch[16 * 128]; // phase1: lists[16][128]; phase2/3: p2T swizzled
    __shared__ int   degBv[16][8];
    __shared__ int   degI[16];
    __shared__ float degF[16];

    const int v0   = blockIdx.x * 16;
    const int tid  = threadIdx.x;
    const int wave = tid >> 6;
    const int lane = tid & 63;
    const int m    = lane & 15;
    const int kq   = lane >> 4;
    const bool full = (v0 + 16 <= N);

    // ---- phase 0: degrees ----
    if (tid < 128) {
        const int vi = tid >> 3, b = tid & 7;
        const int v = v0 + vi;
        int c = (v < N) ? cursor8[(size_t)b * N + v] : 0;
        degBv[vi][b] = (c > CAP8) ? CAP8 : c;
    }
    __syncthreads();
    if (tid < 16) {
        int s = 0;
#pragma unroll
        for (int b = 0; b < 8; b++) s += degBv[tid][b];
        degI[tid] = s; degF[tid] = (float)s;
    }
    __syncthreads();

    // ---- phase 1: per-wave list compaction + asm depth-2 pipelined gather ----
    {
        unsigned short* listT = scratch;
#pragma unroll
        for (int i = 0; i < 4; i++) {
            const int vl = wave * 4 + i;
            const int v  = v0 + vl;
            if (v >= N) continue;                          // wave-uniform
            const int slot0 = lane, slot1 = lane + 64;
            const unsigned short i0 = csr8[((size_t)(slot0 >> 4) * N + v) * CAP8 + (slot0 & 15)];
            const unsigned short i1 = csr8[((size_t)(slot1 >> 4) * N + v) * CAP8 + (slot1 & 15)];
            const bool vd0 = (slot0 & 15) < degBv[vl][slot0 >> 4];
            const bool vd1 = (slot1 & 15) < degBv[vl][slot1 >> 4];
            const unsigned long long m0 = __ballot(vd0);
            const unsigned long long m1 = __ballot(vd1);
            const unsigned long long below = (1ull << lane) - 1ull;
            const int n0 = __popcll(m0);
            if (vd0) listT[vl * 128 + __popcll(m0 & below)] = i0;
            if (vd1) listT[vl * 128 + n0 + __popcll(m1 & below)] = i1;
        }
        // wave-local LDS write->read fence (cross-lane dep the compiler can't see)
        asm volatile("s_waitcnt lgkmcnt(0)" ::: "memory");
        __builtin_amdgcn_sched_barrier(0);

        const int way = lane >> 4, sl = lane & 15;
        const int wvb = wave * 4;

        short8 A0[8], A1[8];
        // depth-2 pipeline: 16 asm loads in flight; vmcnt(8) releases the older vertex's 8.
        GISS(0, A0)
        GISS(1, A1)
        GWAIT(8)  GCONS(0, A0)  GISS(2, A0)
        GWAIT(8)  GCONS(1, A1)  GISS(3, A1)
        GWAIT(8)  GCONS(2, A0)
        GWAIT(0)  GCONS(3, A1)
    }
    __syncthreads();

    // ---- phase 2: GEMM2 -> p2 = gelu((deg*node)@We1^T + nbr@We2^T + deg*be) ----
    {
        f32x4 acc2[2];
#pragma unroll
        for (int ntl = 0; ntl < 2; ntl++) acc2[ntl] = (f32x4){0.f,0.f,0.f,0.f};

#pragma unroll
        for (int kb = 0; kb < 4; kb++) {
            short8 B0[2], B1[2];
#pragma unroll
            for (int ntl = 0; ntl < 2; ntl++) {
                const int j = (wave * 2 + ntl) * 16 + m;
                B0[ntl] = *(const short8*)(Web + (size_t)j * 256 + kb * 32 + kq * 8);
                B1[ntl] = *(const short8*)(Web + (size_t)j * 256 + 128 + kb * 32 + kq * 8);
            }
            const int row = v0 + m;
            short8 an = (full || row < N) ? *(const short8*)(node + (size_t)row * 128 + kb * 32 + kq * 8)
                                          : (short8){0,0,0,0,0,0,0,0};
            short8 ab = *(const short8*)((const char*)nbrT + swz(m, kb * 64 + kq * 16));
            {
                const float dg = degF[m];
#pragma unroll
                for (int k = 0; k < 8; k++)
                    an[k] = (short)f2bf(dg * bf2f((unsigned short)an[k]));
            }
#pragma unroll
            for (int ntl = 0; ntl < 2; ntl++) {
                acc2[ntl] = __builtin_amdgcn_mfma_f32_16x16x32_bf16(an, B0[ntl], acc2[ntl], 0, 0, 0);
                acc2[ntl] = __builtin_amdgcn_mfma_f32_16x16x32_bf16(ab, B1[ntl], acc2[ntl], 0, 0, 0);
            }
        }

        const int ocol = lane & 15;
#pragma unroll
        for (int ntl = 0; ntl < 2; ntl++) {
            const int col = (wave * 2 + ntl) * 16 + ocol;
            const float bval = be[col];
#pragma unroll
            for (int r = 0; r < 4; r++) {
                const int lrow = (lane >> 4) * 4 + r;
                const float dg = degF[lrow];
                const float vv = gelu_exact(acc2[ntl][r] + dg * bval);
                *(unsigned short*)((char*)scratch + swz(lrow, col * 2)) = f2bf(vv);
            }
        }
    }
    __syncthreads();

    // ---- phase 3: GEMM3 -> out = [gelu(node)|gelu(nbr)|gelu(edge_sum)] @ Wu^T + bu ----
    {
        f32x4 acc3[2];
#pragma unroll
        for (int ntl = 0; ntl < 2; ntl++) acc3[ntl] = (f32x4){0.f,0.f,0.f,0.f};

#pragma unroll
        for (int s = 0; s < 3; s++) {
#pragma unroll
            for (int kb = 0; kb < 4; kb++) {
                short8 B3[2];
#pragma unroll
                for (int ntl = 0; ntl < 2; ntl++) {
                    const int j = (wave * 2 + ntl) * 16 + m;
                    B3[ntl] = *(const short8*)(Wub + (size_t)j * 384 + s * 128 + kb * 32 + kq * 8);
                }
                short8 a;
                const int row = v0 + m;
                if (s == 0) {
                    a = (full || row < N) ? *(const short8*)(Apre0 + (size_t)row * 128 + kb * 32 + kq * 8)
                                          : (short8){0,0,0,0,0,0,0,0};
                } else if (s == 1) {
                    a = *(const short8*)((const char*)gnbrT + swz(m, kb * 64 + kq * 16));
                } else {
                    a = *(const short8*)((const char*)scratch + swz(m, kb * 64 + kq * 16));
                }
#pragma unroll
                for (int ntl = 0; ntl < 2; ntl++)
                    acc3[ntl] = __builtin_amdgcn_mfma_f32_16x16x32_bf16(a, B3[ntl], acc3[ntl], 0, 0, 0);
            }
        }

        const int ocol = lane & 15;
#pragma unroll
        for (int ntl = 0; ntl < 2; ntl++) {
            const int col = (wave * 2 + ntl) * 16 + ocol;
            const float bval = bu[col];
#pragma unroll
            for (int r = 0; r < 4; r++) {
                const int row = v0 + (lane >> 4) * 4 + r;
                if (row < N)
                    out[(size_t)row * 128 + col] = acc3[ntl][r] + bval;
            }
        }
    }
}

extern "C" void kernel_launch(void* const* d_in, const int* in_sizes, int n_in,
                              void* d_out, int out_size, void* d_ws, size_t ws_size,
                              hipStream_t stream) {
    const float* x  = (const float*)d_in[0];
    const int*   ei = (const int*)d_in[1];
    const float* Wn = (const float*)d_in[2];
    const float* bn = (const float*)d_in[3];
    const float* We = (const float*)d_in[4];
    const float* be = (const float*)d_in[5];
    const float* Wu = (const float*)d_in[6];
    const float* bu = (const float*)d_in[7];

    const int N = in_sizes[0] / 128;
    const int E = in_sizes[1] / 2;

    char* ws = (char*)d_ws;
    size_t off = 0;
    unsigned short* node  = (unsigned short*)(ws + off); off += (size_t)N * 128 * 2;
    unsigned short* Apre0 = (unsigned short*)(ws + off); off += (size_t)N * 128 * 2;
    off = (off + 255) & ~(size_t)255;
    int* cursor8 = (int*)(ws + off);                     off += (size_t)8 * N * 4;
    off = (off + 255) & ~(size_t)255;
    unsigned short* csr8 = (unsigned short*)(ws + off);  off += (size_t)8 * N * CAP8 * 2;
    off = (off + 255) & ~(size_t)255;
    unsigned short* Wnb = (unsigned short*)(ws + off);   off += (size_t)128 * 128 * 2;
    unsigned short* Web = (unsigned short*)(ws + off);   off += (size_t)128 * 256 * 2;
    unsigned short* Wub = (unsigned short*)(ws + off);   off += (size_t)128 * 384 * 2;

    const int mblocks = (N + 63) / 64;                       // 782
    const int eblocks = (E + 256 * EPT - 1) / (256 * EPT);   // 782 fill blocks
    const int fgroups = (eblocks + 7) / 8;                   // 98
    const int ggroups = (mblocks + 7) / 8;                   // 98
    const int grid_a  = (fgroups + ggroups) * 8;             // 1:1 interleave (even=fill, odd=gemm1)

    // 0. zero cursors + bf16 weights
    init_kernel<<<512, 256, 0, stream>>>(Wn, We, Wu, Wnb, Web, Wub, cursor8, N);
    // A. fill (4 independent atomic chains/thread, XCD-local buckets) interleaved 1:1 with GEMM1
    fused_a<<<grid_a, 256, 0, stream>>>(x, Wnb, bn, node, Apre0, ei, cursor8, csr8, E, N, mblocks);
    // B. asm-pipelined gather (depth-2, 16 loads in flight/wave) + GEMM2 + GEMM3 per 16-row tile
    fused_b<<<(N + 15) / 16, 256, 0, stream>>>(cursor8, csr8, node, Apre0, Web, be, Wub, bu, (float*)d_out, N);
}

// Round 13
// 232.166 us; speedup vs baseline: 1.0720x; 1.0720x over previous
//
#include <hip/hip_runtime.h>
#include <hip/hip_bf16.h>
#include <math.h>

typedef __attribute__((ext_vector_type(8))) short short8;
typedef __attribute__((ext_vector_type(4))) float f32x4;

// 8-way bucketed CSR, entries ushort (dst < 65536; N=50000).
// bucket = blockIdx&7 (~XCD under round-robin). Layout [N][8][CAP8] (r3's measured-best
// for the fill, and contiguous per-vertex for fused_b's compaction read).
#define CAP8 16

__device__ __forceinline__ float bf2f(unsigned short u) {
    union { unsigned int i; float f; } c; c.i = ((unsigned int)u) << 16; return c.f;
}
__device__ __forceinline__ unsigned short f2bf(float f) {
    __hip_bfloat16 h = __float2bfloat16(f);   // RNE
    union { __hip_bfloat16 h; unsigned short u; } c; c.h = h; return c.u;
}
__device__ __forceinline__ float gelu_exact(float x) {
    return 0.5f * x * (1.0f + erff(x * 0.7071067811865475f));
}
__device__ __forceinline__ short8 ldcvt8(const float* p) {
    float4 f0 = *(const float4*)p;
    float4 f1 = *(const float4*)(p + 4);
    short8 a;
    a[0] = (short)f2bf(f0.x); a[1] = (short)f2bf(f0.y);
    a[2] = (short)f2bf(f0.z); a[3] = (short)f2bf(f0.w);
    a[4] = (short)f2bf(f1.x); a[5] = (short)f2bf(f1.y);
    a[6] = (short)f2bf(f1.z); a[7] = (short)f2bf(f1.w);
    return a;
}
// XOR swizzle for [rows][128] bf16 LDS tile (row stride 256B): 16B-granular, bijective per 8-row stripe.
__device__ __forceinline__ int swz(int row, int colbyte) {
    return row * 256 + (colbyte ^ ((row & 7) << 4));
}

// volatile asm 16B global load: cannot be sunk/reordered by the compiler (the r5 failure mode).
__device__ __forceinline__ short8 ga16(const unsigned short* p) {
    short8 r;
    asm volatile("global_load_dwordx4 %0, %1, off" : "=v"(r) : "v"(p));
    return r;
}
#define GWAIT(NVM) { \
    asm volatile("s_waitcnt vmcnt(" #NVM ")" ::: "memory"); \
    __builtin_amdgcn_sched_barrier(0); }

__device__ __forceinline__ int detect_flag(const int* ei, int E) {
    int orv = 0;
    int lim = (E < 64) ? E : 64;
    for (int i = 0; i < lim; i++) orv |= ei[2 * i + 1];
    return (orv == 0) ? 1 : 0;
}
__device__ __forceinline__ int ld_src(const int* ei, int flag, int E, int e) {
    if (flag) { int2 p = *(const int2*)(ei + 2 * (size_t)e); return p.x; }
    return ei[e];
}
__device__ __forceinline__ int ld_dst(const int* ei, int flag, int E, int e) {
    if (flag) { int2 p = *(const int2*)(ei + 2 * (size_t)(E + e)); return p.x; }
    return ei[E + e];
}

// ---------------- init: zero cursors + convert weights to bf16 ----------------
__launch_bounds__(256)
__global__ void init_kernel(const float* __restrict__ Wn, const float* __restrict__ We,
                            const float* __restrict__ Wu,
                            unsigned short* __restrict__ Wnb, unsigned short* __restrict__ Web,
                            unsigned short* __restrict__ Wub,
                            int* __restrict__ cursor8, int N) {
    const int stride = gridDim.x * 256;
    const int t = blockIdx.x * 256 + threadIdx.x;
    for (int i = t; i < 8 * N; i += stride) cursor8[i] = 0;
    for (int i = t; i < 128 * 128; i += stride) Wnb[i] = f2bf(Wn[i]);
    for (int i = t; i < 128 * 256; i += stride) Web[i] = f2bf(We[i]);
    for (int i = t; i < 128 * 384; i += stride) Wub[i] = f2bf(Wu[i]);
}

// ---------------- GEMM1 body: node = x@Wn^T + bn (bf16); Apre0 = gelu(node) ----------------
__device__ __forceinline__ void gemm1_body(int bid,
                                           const float* __restrict__ x,
                                           const unsigned short* __restrict__ Wnb,  // [128][128] bf16
                                           const float* __restrict__ bias,
                                           unsigned short* __restrict__ node,
                                           unsigned short* __restrict__ Apre0,
                                           int N) {
    const int v0 = bid * 64;
    const int wave = threadIdx.x >> 6;
    const int lane = threadIdx.x & 63;
    const int m    = lane & 15;
    const int kq   = lane >> 4;

    short8 B[2][4];
#pragma unroll
    for (int ntl = 0; ntl < 2; ntl++) {
        const int j = (wave * 2 + ntl) * 16 + m;
#pragma unroll
        for (int kb = 0; kb < 4; kb++)
            B[ntl][kb] = *(const short8*)(Wnb + (size_t)j * 128 + kb * 32 + kq * 8);
    }

    f32x4 acc[4][2];
#pragma unroll
    for (int mt = 0; mt < 4; mt++)
#pragma unroll
        for (int ntl = 0; ntl < 2; ntl++) acc[mt][ntl] = (f32x4){0.f,0.f,0.f,0.f};

#pragma unroll
    for (int kb = 0; kb < 4; kb++) {
#pragma unroll
        for (int mt = 0; mt < 4; mt++) {
            const int row = v0 + mt * 16 + m;
            short8 a = (short8){0,0,0,0,0,0,0,0};
            if (row < N) a = ldcvt8(x + (size_t)row * 128 + kb * 32 + kq * 8);
#pragma unroll
            for (int ntl = 0; ntl < 2; ntl++)
                acc[mt][ntl] = __builtin_amdgcn_mfma_f32_16x16x32_bf16(a, B[ntl][kb], acc[mt][ntl], 0, 0, 0);
        }
    }

    const int ocol = lane & 15;
#pragma unroll
    for (int mt = 0; mt < 4; mt++) {
#pragma unroll
        for (int ntl = 0; ntl < 2; ntl++) {
            const int col = (wave * 2 + ntl) * 16 + ocol;
            const float bval = bias[col];
#pragma unroll
            for (int r = 0; r < 4; r++) {
                const int row = v0 + mt * 16 + (lane >> 4) * 4 + r;
                if (row < N) {
                    const float v = acc[mt][ntl][r] + bval;
                    node[(size_t)row * 128 + col]  = f2bf(v);
                    Apre0[(size_t)row * 128 + col] = f2bf(gelu_exact(v));
                }
            }
        }
    }
}

// ---------------- Kernel A: fill (1 edge/thread, r3's directly-measured 68-75us structure) ----
// 4:1 fill:gemm1 interleave in groups of 8 (bucket = blockIdx&7 uniform per XCD).
__launch_bounds__(256)
__global__ void fused_a(const float* __restrict__ x,
                        const unsigned short* __restrict__ Wnb,
                        const float* __restrict__ bn,
                        unsigned short* __restrict__ node,
                        unsigned short* __restrict__ Apre0,
                        const int* __restrict__ ei,
                        int* __restrict__ cursor8,          // [8][N]
                        unsigned short* __restrict__ csr8,  // [N][8][CAP8] ushort (r3 layout)
                        int E, int N, int mblocks) {
    const int grp = blockIdx.x >> 3;
    if ((grp % 5) == 2) {
        const int mid = ((grp - 2) / 5) * 8 + (int)(blockIdx.x & 7);
        if (mid < mblocks) gemm1_body(mid, x, Wnb, bn, node, Apre0, N);
        return;
    }
    __shared__ int sflag;
    if (threadIdx.x == 0) sflag = detect_flag(ei, E);
    __syncthreads();
    const int fgrp = grp - (grp + 2) / 5;                 // fill-group index (contiguous)
    const int b = (int)(blockIdx.x & 7);                  // ~XCD id under round-robin dispatch
    const int e = (fgrp * 8 + b) * 256 + (int)threadIdx.x;
    if (e >= E) return;
    const int s = ld_src(ei, sflag, E, e);
    const int d = ld_dst(ei, sflag, E, e);
    if ((unsigned)s >= (unsigned)N || (unsigned)d >= (unsigned)N) return;
    const int p = atomicAdd(&cursor8[(size_t)b * N + s], 1);
    if (p < CAP8) csr8[(size_t)s * 128 + b * CAP8 + p] = (unsigned short)d;
}

// ---- asm-pipelined gather (fused, M=32): wave owns 8 vertices; 8 volatile-asm loads/vertex
// (rows way+4u, u<8 covers deg<=32, sentinel row 0 beyond); depth-2 pipeline -> 16 in flight.
#define GISS(I, BUF) { \
    const int vl_ = wv8 + (I); \
    const int dg_ = degI[vl_]; \
    _Pragma("unroll") \
    for (int u = 0; u < 8; u++) { \
        const int r_  = way + 4 * u; \
        const int id_ = (r_ < dg_) ? (int)listT[vl_ * 128 + r_] : 0; \
        BUF[u] = ga16(node + (size_t)id_ * 128 + sl * 8); \
    } }

#define GCONS(I, BUF) { \
    const int vl_ = wv8 + (I); \
    const int v_  = v0 + vl_; \
    const int dg_ = degI[vl_]; \
    float acc_[8] = {0.f,0.f,0.f,0.f,0.f,0.f,0.f,0.f}; \
    _Pragma("unroll") \
    for (int u = 0; u < 8; u++) { \
        if (way + 4 * u < dg_) { \
            _Pragma("unroll") \
            for (int e = 0; e < 8; e++) acc_[e] += bf2f((unsigned short)BUF[u][e]); \
        } } \
    if (__builtin_expect(dg_ > 32, 0)) {   /* P~1e-4; compiler's own waits cover these loads */ \
        for (int n_ = 32 + way; n_ < dg_; n_ += 4) { \
            const int id_ = (int)listT[vl_ * 128 + n_]; \
            short8 t_ = *(const short8*)(node + (size_t)id_ * 128 + sl * 8); \
            _Pragma("unroll") \
            for (int e = 0; e < 8; e++) acc_[e] += bf2f((unsigned short)t_[e]); \
        } } \
    _Pragma("unroll") \
    for (int e = 0; e < 8; e++) { \
        acc_[e] += __shfl_xor(acc_[e], 16); \
        acc_[e] += __shfl_xor(acc_[e], 32); \
    } \
    if (v_ < N) { \
        if (way == 0) { \
            short8 o_; \
            _Pragma("unroll") \
            for (int e = 0; e < 8; e++) o_[e] = (short)f2bf(acc_[e]); \
            *(short8*)((char*)nbrT + swz(vl_, sl * 16)) = o_; \
        } else if (way == 1) { \
            short8 o_; \
            _Pragma("unroll") \
            for (int e = 0; e < 8; e++) o_[e] = (short)f2bf(gelu_exact(acc_[e])); \
            *(short8*)((char*)gnbrT + swz(vl_, sl * 16)) = o_; \
        } } }

// ---------------- Kernel B: asm gather -> GEMM2 -> GEMM3 per 32-row tile (r9 verbatim) ----------
__launch_bounds__(256)
__global__ void fused_b(const int* __restrict__ cursor8,
                        const unsigned short* __restrict__ csr8,   // [N][8][CAP8]
                        const unsigned short* __restrict__ node,
                        const unsigned short* __restrict__ Apre0,
                        const unsigned short* __restrict__ Web,  // [128][256] bf16
                        const float* __restrict__ be,
                        const unsigned short* __restrict__ Wub,  // [128][384] bf16
                        const float* __restrict__ bu,
                        float* __restrict__ out, int N) {
    __shared__ unsigned short nbrT [32 * 128];   // raw nbr sum bf16, swizzled
    __shared__ unsigned short gnbrT[32 * 128];   // gelu(nbr sum) bf16, swizzled
    __shared__ unsigned short scratch[32 * 128]; // phase1: lists[32][128]; phase2/3: p2T swizzled
    __shared__ int   degBv[32][8];
    __shared__ int   degI[32];
    __shared__ float degF[32];

    const int v0   = blockIdx.x * 32;
    const int tid  = threadIdx.x;
    const int wave = tid >> 6;
    const int lane = tid & 63;
    const int m    = lane & 15;
    const int kq   = lane >> 4;
    const bool full = (v0 + 32 <= N);

    // ---- phase 0: degrees ----
    {
        const int vi = tid >> 3, b = tid & 7;
        const int v = v0 + vi;
        int c = (v < N) ? cursor8[(size_t)b * N + v] : 0;
        degBv[vi][b] = (c > CAP8) ? CAP8 : c;
    }
    __syncthreads();
    if (tid < 32) {
        int s = 0;
#pragma unroll
        for (int b = 0; b < 8; b++) s += degBv[tid][b];
        degI[tid] = s; degF[tid] = (float)s;
    }
    __syncthreads();

    // ---- phase 1: per-wave list compaction ([N][8] layout: contiguous 128B/vertex) + gather ----
    {
        unsigned short* listT = scratch;
#pragma unroll
        for (int i = 0; i < 8; i++) {
            const int vl = wave * 8 + i;
            const int v  = v0 + vl;
            if (v >= N) continue;                          // wave-uniform
            const int slot0 = lane, slot1 = lane + 64;
            const unsigned short i0 = csr8[(size_t)v * 128 + slot0];
            const unsigned short i1 = csr8[(size_t)v * 128 + slot1];
            const bool vd0 = (slot0 & 15) < degBv[vl][slot0 >> 4];
            const bool vd1 = (slot1 & 15) < degBv[vl][slot1 >> 4];
            const unsigned long long m0 = __ballot(vd0);
            const unsigned long long m1 = __ballot(vd1);
            const unsigned long long below = (1ull << lane) - 1ull;
            const int n0 = __popcll(m0);
            if (vd0) listT[vl * 128 + __popcll(m0 & below)] = i0;
            if (vd1) listT[vl * 128 + n0 + __popcll(m1 & below)] = i1;
        }
        // wave-local LDS write->read fence (cross-lane dep the compiler can't see)
        asm volatile("s_waitcnt lgkmcnt(0)" ::: "memory");
        __builtin_amdgcn_sched_barrier(0);

        const int way = lane >> 4, sl = lane & 15;
        const int wv8 = wave * 8;

        short8 A0[8], A1[8];
        // depth-2 pipeline: 16 asm loads in flight; vmcnt(8) releases the older vertex's 8.
        GISS(0, A0)
        GISS(1, A1)
        GWAIT(8)  GCONS(0, A0)  GISS(2, A0)
        GWAIT(8)  GCONS(1, A1)  GISS(3, A1)
        GWAIT(8)  GCONS(2, A0)  GISS(4, A0)
        GWAIT(8)  GCONS(3, A1)  GISS(5, A1)
        GWAIT(8)  GCONS(4, A0)  GISS(6, A0)
        GWAIT(8)  GCONS(5, A1)  GISS(7, A1)
        GWAIT(8)  GCONS(6, A0)
        GWAIT(0)  GCONS(7, A1)
    }
    __syncthreads();

    // ---- phase 2: GEMM2 -> p2 = gelu((deg*node)@We1^T + nbr@We2^T + deg*be) ----
    {
        f32x4 acc2[2][2];
#pragma unroll
        for (int mt = 0; mt < 2; mt++)
#pragma unroll
            for (int ntl = 0; ntl < 2; ntl++) acc2[mt][ntl] = (f32x4){0.f,0.f,0.f,0.f};

#pragma unroll
        for (int kb = 0; kb < 4; kb++) {
            short8 B0[2], B1[2], an[2], ab[2];
#pragma unroll
            for (int ntl = 0; ntl < 2; ntl++) {
                const int j = (wave * 2 + ntl) * 16 + m;
                B0[ntl] = *(const short8*)(Web + (size_t)j * 256 + kb * 32 + kq * 8);
                B1[ntl] = *(const short8*)(Web + (size_t)j * 256 + 128 + kb * 32 + kq * 8);
            }
#pragma unroll
            for (int mt = 0; mt < 2; mt++) {
                const int lrow = mt * 16 + m;
                const int row  = v0 + lrow;
                an[mt] = (full || row < N) ? *(const short8*)(node + (size_t)row * 128 + kb * 32 + kq * 8)
                                           : (short8){0,0,0,0,0,0,0,0};
                ab[mt] = *(const short8*)((const char*)nbrT + swz(lrow, kb * 64 + kq * 16));
            }
#pragma unroll
            for (int mt = 0; mt < 2; mt++) {
                const float dg = degF[mt * 16 + m];
#pragma unroll
                for (int k = 0; k < 8; k++)
                    an[mt][k] = (short)f2bf(dg * bf2f((unsigned short)an[mt][k]));
            }
#pragma unroll
            for (int mt = 0; mt < 2; mt++)
#pragma unroll
                for (int ntl = 0; ntl < 2; ntl++) {
                    acc2[mt][ntl] = __builtin_amdgcn_mfma_f32_16x16x32_bf16(an[mt], B0[ntl], acc2[mt][ntl], 0, 0, 0);
                    acc2[mt][ntl] = __builtin_amdgcn_mfma_f32_16x16x32_bf16(ab[mt], B1[ntl], acc2[mt][ntl], 0, 0, 0);
                }
        }

        const int ocol = lane & 15;
#pragma unroll
        for (int mt = 0; mt < 2; mt++) {
#pragma unroll
            for (int ntl = 0; ntl < 2; ntl++) {
                const int col = (wave * 2 + ntl) * 16 + ocol;
                const float bval = be[col];
#pragma unroll
                for (int r = 0; r < 4; r++) {
                    const int lrow = mt * 16 + (lane >> 4) * 4 + r;
                    const float dg = degF[lrow];
                    const float vv = gelu_exact(acc2[mt][ntl][r] + dg * bval);
                    *(unsigned short*)((char*)scratch + swz(lrow, col * 2)) = f2bf(vv);
                }
            }
        }
    }
    __syncthreads();

    // ---- phase 3: GEMM3 -> out = [gelu(node)|gelu(nbr)|gelu(edge_sum)] @ Wu^T + bu ----
    {
        f32x4 acc3[2][2];
#pragma unroll
        for (int mt = 0; mt < 2; mt++)
#pragma unroll
            for (int ntl = 0; ntl < 2; ntl++) acc3[mt][ntl] = (f32x4){0.f,0.f,0.f,0.f};

#pragma unroll
        for (int s = 0; s < 3; s++) {
#pragma unroll
            for (int kb = 0; kb < 4; kb++) {
                short8 B3[2], a[2];
#pragma unroll
                for (int ntl = 0; ntl < 2; ntl++) {
                    const int j = (wave * 2 + ntl) * 16 + m;
                    B3[ntl] = *(const short8*)(Wub + (size_t)j * 384 + s * 128 + kb * 32 + kq * 8);
                }
#pragma unroll
                for (int mt = 0; mt < 2; mt++) {
                    const int lrow = mt * 16 + m;
                    const int row  = v0 + lrow;
                    if (s == 0) {
                        a[mt] = (full || row < N) ? *(const short8*)(Apre0 + (size_t)row * 128 + kb * 32 + kq * 8)
                                                  : (short8){0,0,0,0,0,0,0,0};
                    } else if (s == 1) {
                        a[mt] = *(const short8*)((const char*)gnbrT + swz(lrow, kb * 64 + kq * 16));
                    } else {
                        a[mt] = *(const short8*)((const char*)scratch + swz(lrow, kb * 64 + kq * 16));
                    }
                }
#pragma unroll
                for (int mt = 0; mt < 2; mt++)
#pragma unroll
                    for (int ntl = 0; ntl < 2; ntl++)
                        acc3[mt][ntl] = __builtin_amdgcn_mfma_f32_16x16x32_bf16(a[mt], B3[ntl], acc3[mt][ntl], 0, 0, 0);
            }
        }

        const int ocol = lane & 15;
#pragma unroll
        for (int mt = 0; mt < 2; mt++) {
#pragma unroll
            for (int ntl = 0; ntl < 2; ntl++) {
                const int col = (wave * 2 + ntl) * 16 + ocol;
                const float bval = bu[col];
#pragma unroll
                for (int r = 0; r < 4; r++) {
                    const int row = v0 + mt * 16 + (lane >> 4) * 4 + r;
                    if (row < N)
                        out[(size_t)row * 128 + col] = acc3[mt][ntl][r] + bval;
                }
            }
        }
    }
}

extern "C" void kernel_launch(void* const* d_in, const int* in_sizes, int n_in,
                              void* d_out, int out_size, void* d_ws, size_t ws_size,
                              hipStream_t stream) {
    const float* x  = (const float*)d_in[0];
    const int*   ei = (const int*)d_in[1];
    const float* Wn = (const float*)d_in[2];
    const float* bn = (const float*)d_in[3];
    const float* We = (const float*)d_in[4];
    const float* be = (const float*)d_in[5];
    const float* Wu = (const float*)d_in[6];
    const float* bu = (const float*)d_in[7];

    const int N = in_sizes[0] / 128;
    const int E = in_sizes[1] / 2;

    char* ws = (char*)d_ws;
    size_t off = 0;
    unsigned short* node  = (unsigned short*)(ws + off); off += (size_t)N * 128 * 2;
    unsigned short* Apre0 = (unsigned short*)(ws + off); off += (size_t)N * 128 * 2;
    off = (off + 255) & ~(size_t)255;
    int* cursor8 = (int*)(ws + off);                     off += (size_t)8 * N * 4;
    off = (off + 255) & ~(size_t)255;
    unsigned short* csr8 = (unsigned short*)(ws + off);  off += (size_t)N * 8 * CAP8 * 2;
    off = (off + 255) & ~(size_t)255;
    unsigned short* Wnb = (unsigned short*)(ws + off);   off += (size_t)128 * 128 * 2;
    unsigned short* Web = (unsigned short*)(ws + off);   off += (size_t)128 * 256 * 2;
    unsigned short* Wub = (unsigned short*)(ws + off);   off += (size_t)128 * 384 * 2;

    const int mblocks = (N + 63) / 64;                   // 782
    const int eblocks = (E + 255) / 256;                 // 3125 fill blocks (1 edge/thread)
    const int fgroups = (eblocks + 7) / 8;               // 391
    const int ggroups = (mblocks + 7) / 8;               // 98
    const int tgroups = fgroups + ggroups;               // 489 (gemm1 at grp%5==2)
    const int grid_a  = tgroups * 8;

    // 0. zero cursors + bf16 weights
    init_kernel<<<512, 256, 0, stream>>>(Wn, We, Wu, Wnb, Web, Wub, cursor8, N);
    // A. fill (1 atomic/edge, r3's measured 68-75us structure, [N][8] csr) interleaved 4:1 w/ GEMM1
    fused_a<<<grid_a, 256, 0, stream>>>(x, Wnb, bn, node, Apre0, ei, cursor8, csr8, E, N, mblocks);
    // B. asm-pipelined gather (depth-2, 16 loads in flight/wave) + GEMM2 + GEMM3 per 32-row tile
    fused_b<<<(N + 31) / 32, 256, 0, stream>>>(cursor8, csr8, node, Apre0, Web, be, Wub, bu, (float*)d_out, N);
}